// Round 10
// baseline (153.697 us; speedup 1.0000x reference)
//
#include <hip/hip_runtime.h>
#include <hip/hip_bf16.h>
#include <hip/hip_fp16.h>

typedef __attribute__((ext_vector_type(8))) short bf16x8;
typedef __attribute__((ext_vector_type(8))) _Float16 f16x8;
typedef __attribute__((ext_vector_type(4))) float f32x4;

// Swizzled byte address for 128-byte rows: XOR row bits into the 16B-slot index.
#define SWZ(row, byteofs) (((row)*128) + ((byteofs) ^ (((row)&7)<<4)))

__device__ __forceinline__ unsigned pk2(float a, float b){
  __hip_bfloat162 h = __float22bfloat162_rn(make_float2(a, b));   // v_cvt_pk_bf16_f32
  unsigned u; __builtin_memcpy(&u, &h, 4);
  return u;
}

__device__ __forceinline__ unsigned pkh(float a, float b){
  auto h = __builtin_amdgcn_cvt_pkrtz(a, b);                      // v_cvt_pkrtz_f16_f32
  unsigned u; __builtin_memcpy(&u, &h, 4);
  return u;
}

__device__ __forceinline__ void gld16(const void* g, void* l){
  __builtin_amdgcn_global_load_lds((const __attribute__((address_space(1))) void*)g,
                                   (__attribute__((address_space(3))) void*)l, 16, 0, 0);
}

union bfpack { bf16x8 v; unsigned u[4]; uint4 q; };

// ---------------- mask -> byte mask (0xFF per kept (q,k)) ----------------
__global__ __launch_bounds__(256) void maskex_kernel(const int* __restrict__ mask,
                                                     unsigned* __restrict__ mex){
  size_t i = (size_t)blockIdx.x * 256 + threadIdx.x;   // 16 elements per thread
  const int4* mp = reinterpret_cast<const int4*>(mask) + i * 4;
  int4 a = mp[0], b = mp[1], c = mp[2], d = mp[3];
  uint4 o;
  o.x = (a.x?0xFFu:0u)|(a.y?0xFF00u:0u)|(a.z?0xFF0000u:0u)|(a.w?0xFF000000u:0u);
  o.y = (b.x?0xFFu:0u)|(b.y?0xFF00u:0u)|(b.z?0xFF0000u:0u)|(b.w?0xFF000000u:0u);
  o.z = (c.x?0xFFu:0u)|(c.y?0xFF00u:0u)|(c.z?0xFF0000u:0u)|(c.w?0xFF000000u:0u);
  o.w = (d.x?0xFFu:0u)|(d.y?0xFF00u:0u)|(d.z?0xFF0000u:0u)|(d.w?0xFF000000u:0u);
  reinterpret_cast<uint4*>(mex)[i] = o;
}

// ---------------- W fp32 -> bf16 ----------------
__global__ __launch_bounds__(256) void wconv_kernel(const float* __restrict__ W,
                                                    unsigned short* __restrict__ Wb){
  int i = blockIdx.x * 256 + threadIdx.x;
  float4 f = reinterpret_cast<const float4*>(W)[i];
  uint2 o = make_uint2(pk2(f.x, f.y), pk2(f.z, f.w));
  reinterpret_cast<uint2*>(Wb)[i] = o;
}

// ---------------- K permute: (n, L, h*64) f32 -> (n, h, L, 64) bf16 ----------------
__global__ __launch_bounds__(256) void permqk_kernel(const float* __restrict__ src,
                                                     unsigned short* __restrict__ dst){
  int w = blockIdx.x * 4 + (threadIdx.x >> 6);   // 16384 waves: n(8) x h(16) x l8(128)
  int lane = threadIdx.x & 63;
  int n = w >> 11, h = (w >> 7) & 15, l8 = w & 127;
  int l = l8 * 8 + (lane >> 3);
  int dch = (lane & 7) * 8;
  const float* sp = src + ((size_t)n * 1024 + l) * 1024 + h * 64 + dch;
  float4 a = *reinterpret_cast<const float4*>(sp);
  float4 b = *reinterpret_cast<const float4*>(sp + 4);
  uint4 o = make_uint4(pk2(a.x,a.y), pk2(a.z,a.w), pk2(b.x,b.y), pk2(b.z,b.w));
  *reinterpret_cast<uint4*>(dst + (((size_t)n * 16 + h) * 1024 + l) * 64 + dch) = o;
}

// ---- V permute+transpose: (n, L, h*64) f32 -> (n, h, 64, L) f16, + per-tile d-sums ----
__global__ __launch_bounds__(256) void permv_kernel(const float* __restrict__ src,
                                                    unsigned short* __restrict__ dst,
                                                    float* __restrict__ Vpart){
  __shared__ __attribute__((aligned(16))) unsigned short T[64*64];  // [l][d] f16 bits, swizzled
  __shared__ float red[256];
  int bid = blockIdx.x;                   // 2048 = n(8) x h(16) x ltile(16)
  int n = bid >> 8, h = (bid >> 4) & 15, lt = bid & 15, l0 = lt * 64;
  int t = threadIdx.x;
  {
    int l = t >> 2, dseg = t & 3;
    const float* sp = src + ((size_t)n * 1024 + l0 + l) * 1024 + h * 64 + dseg * 16;
    float4 f0 = *reinterpret_cast<const float4*>(sp + 0);
    float4 f1 = *reinterpret_cast<const float4*>(sp + 4);
    float4 f2 = *reinterpret_cast<const float4*>(sp + 8);
    float4 f3 = *reinterpret_cast<const float4*>(sp + 12);
    uint4 lo = make_uint4(pkh(f0.x,f0.y), pkh(f0.z,f0.w), pkh(f1.x,f1.y), pkh(f1.z,f1.w));
    uint4 hi = make_uint4(pkh(f2.x,f2.y), pkh(f2.z,f2.w), pkh(f3.x,f3.y), pkh(f3.z,f3.w));
    *reinterpret_cast<uint4*>((char*)T + SWZ(l, dseg*32))      = lo;
    *reinterpret_cast<uint4*>((char*)T + SWZ(l, dseg*32 + 16)) = hi;
  }
  __syncthreads();
  {
    int d = t >> 2, lseg = t & 3;
    float s = 0.f;
    for (int j = 0; j < 2; ++j){
      bf16x8 wv;
      #pragma unroll
      for (int i = 0; i < 8; ++i){
        int l = lseg*16 + j*8 + i;        // l&7 == i (static per unrolled i)
        wv[i] = *(const short*)((const char*)T + (size_t)l*128 + ((d*2) ^ (i<<4)));
      }
      *reinterpret_cast<bf16x8*>(dst + (((size_t)n * 16 + h) * 64 + d) * 1024 + l0 + lseg*16 + j*8) = wv;
      #pragma unroll
      for (int i = 0; i < 8; i += 2){
        unsigned u = (unsigned)(unsigned short)wv[i] | ((unsigned)(unsigned short)wv[i+1] << 16);
        __half2 hh; __builtin_memcpy(&hh, &u, 4);
        float2 f = __half22float2(hh);
        s += f.x + f.y;
      }
    }
    red[t] = s;
    __syncthreads();
    if (lseg == 0)
      Vpart[((size_t)(n*16 + h)*64 + d)*16 + lt] = red[t] + red[t+1] + red[t+2] + red[t+3];
  }
}

// ---------------- flash attention (swapped QK^T, P'=p-1, f16 PV, ones-MFMA denom) ------
// grid: 2048 blocks = (n:8) x (h:16) x (qb:16), 256 threads (4 waves x 16 q-rows)
__global__ __launch_bounds__(256) void attn_kernel(
    const float* __restrict__ Q, const unsigned short* __restrict__ Kb,
    const unsigned short* __restrict__ Vtg, const unsigned char* __restrict__ Mex8,
    const float* __restrict__ Vpart, unsigned short* __restrict__ Obf)
{
  __shared__ __attribute__((aligned(16))) unsigned short Kt[2][64*64];   // [key][d] bf16, swizzled
  __shared__ __attribute__((aligned(16))) unsigned short Vt[2][64*64];   // [d][key] f16, swizzled
  __shared__ __attribute__((aligned(16))) unsigned short Pl[4][16*64];   // per-wave P' [q][key] f16

  int bid = blockIdx.x;
  int wg = ((bid & 7) << 8) | (bid >> 3);   // XCD-contiguous chunks of 256
  int qb = wg & 15, h = (wg >> 4) & 15, n = wg >> 8;

  int tid = threadIdx.x, wid = tid >> 6, lane = tid & 63, lg = lane >> 4, lc = lane & 15;
  int qbase = qb * 64 + wid * 16;

  const unsigned short* Kh = Kb  + ((size_t)(n*16 + h)) * 1024 * 64;
  const unsigned short* Vh = Vtg + ((size_t)(n*16 + h)) * 64 * 1024;
  const char* m8 = (const char*)Mex8 + ((size_t)(n*1024 + qbase + lc)) * 1024;

  // Q fragment (dual-use A/B layout): lane holds Q[q=lc][d=lg*8+j+32c]
  bf16x8 qf[2];
  {
    const float* qp = Q + (size_t)(n*1024 + qbase + lc) * 1024 + h*64;
    #pragma unroll
    for (int c = 0; c < 2; ++c){
      float4 a0 = *reinterpret_cast<const float4*>(qp + c*32 + lg*8);
      float4 a1 = *reinterpret_cast<const float4*>(qp + c*32 + lg*8 + 4);
      bfpack pk;
      pk.u[0] = pk2(a0.x,a0.y); pk.u[1] = pk2(a0.z,a0.w);
      pk.u[2] = pk2(a1.x,a1.y); pk.u[3] = pk2(a1.z,a1.w);
      qf[c] = pk.v;
    }
  }

  // staging slots: slot s -> LDS byte 16s == SWZ(row=s>>3, col=(s&7)*16 ^ ((row&7)<<4))
  const int s0 = tid, s1 = tid + 256;
  const int r0 = s0 >> 3, c0 = ((s0 & 7) * 16) ^ ((r0 & 7) << 4);
  const int r1 = s1 >> 3, c1 = ((s1 & 7) * 16) ^ ((r1 & 7) << 4);

#define STAGE(KB, BUF) do { \
    gld16((const char*)Kh + ((size_t)((KB)*64 + r0) * 128 + c0), (char*)Kt[BUF] + s0*16); \
    gld16((const char*)Kh + ((size_t)((KB)*64 + r1) * 128 + c1), (char*)Kt[BUF] + s1*16); \
    gld16((const char*)Vh + ((size_t)r0 * 2048 + (KB)*128 + c0), (char*)Vt[BUF] + s0*16); \
    gld16((const char*)Vh + ((size_t)r1 * 2048 + (KB)*128 + c1), (char*)Vt[BUF] + s1*16); \
  } while(0)

  // P' write addresses (row=q=lc, col byte = (t*16+lg*4)*2, swizzled) — loop-invariant
  int pa[4];
  #pragma unroll
  for (int t = 0; t < 4; ++t)
    pa[t] = lc*128 + ((((t*16 + lg*4)*2)) ^ ((lc & 7) << 4));

  // acc init = Vsum[d] (the Σ_k 1·V[k][d] term), accd = Σ_k P'
  f32x4 acc[4], accd = (f32x4){0.f,0.f,0.f,0.f};
  {
    const float* vp0 = Vpart + (size_t)(n*16 + h) * 64 * 16;
    #pragma unroll
    for (int t2 = 0; t2 < 4; ++t2){
      const float4* pp = reinterpret_cast<const float4*>(vp0 + (t2*16 + lc)*16);
      float4 s0v = pp[0], s1v = pp[1], s2v = pp[2], s3v = pp[3];
      float v = ((s0v.x+s0v.y)+(s0v.z+s0v.w)) + ((s1v.x+s1v.y)+(s1v.z+s1v.w))
              + ((s2v.x+s2v.y)+(s2v.z+s2v.w)) + ((s3v.x+s3v.y)+(s3v.z+s3v.w));
      acc[t2] = (f32x4){v,v,v,v};
    }
  }

  const float c2 = 0.045084220027780106f;   // log2(e)/32
  const __half2 hone2 = __floats2half2_rn(1.f, 1.f);
  const f16x8 onesf = {(_Float16)1.f,(_Float16)1.f,(_Float16)1.f,(_Float16)1.f,
                       (_Float16)1.f,(_Float16)1.f,(_Float16)1.f,(_Float16)1.f};

  STAGE(0, 0);
  int cur = 0;

  for (int kb = 0; kb < 16; ++kb){
    __syncthreads();                      // drains vmcnt -> buf[cur] ready; prev reads done
    if (kb < 15) STAGE(kb + 1, cur ^ 1);  // in flight under this tile's compute

    // byte-masks for this thread's q-row: keys 16t+4lg+0..3 per t
    unsigned msk[4];
    #pragma unroll
    for (int t = 0; t < 4; ++t)
      msk[t] = *reinterpret_cast<const unsigned*>(m8 + kb*64 + t*16 + lg*4);

    // ---- Sw = K . Q^T  (swapped: lane holds S[key=16t+lg*4+r][q=lc]) ----
    f32x4 Sw[4];
    #pragma unroll
    for (int t = 0; t < 4; ++t) Sw[t] = (f32x4){0.f,0.f,0.f,0.f};
    __builtin_amdgcn_s_setprio(1);
    #pragma unroll
    for (int t = 0; t < 4; ++t)
      #pragma unroll
      for (int c = 0; c < 2; ++c){
        bf16x8 kf = *reinterpret_cast<const bf16x8*>((const char*)Kt[cur] + SWZ(t*16 + lc, lg*16 + c*64));
        Sw[t] = __builtin_amdgcn_mfma_f32_16x16x32_bf16(kf, qf[c], Sw[t], 0, 0, 0);
      }
    __builtin_amdgcn_s_setprio(0);

    // ---- P' = mask & (exp2(S*c2) - 1), packed f16; masked -> exactly 0 ----
    unsigned short* pl = &Pl[wid][0];
    #pragma unroll
    for (int t = 0; t < 4; ++t){
      unsigned u01 = pkh(Sw[t][0]*c2, Sw[t][1]*c2);
      unsigned u23 = pkh(Sw[t][2]*c2, Sw[t][3]*c2);
      __half2 h01, h23;
      __builtin_memcpy(&h01, &u01, 4); __builtin_memcpy(&h23, &u23, 4);
      h01 = __hsub2(h2exp2(h01), hone2);
      h23 = __hsub2(h2exp2(h23), hone2);
      __builtin_memcpy(&u01, &h01, 4); __builtin_memcpy(&u23, &h23, 4);
      u01 &= __builtin_amdgcn_perm(0u, msk[t], 0x01010000u);   // bytes {0,0,1,1} -> pair mask
      u23 &= __builtin_amdgcn_perm(0u, msk[t], 0x03030202u);   // bytes {2,2,3,3}
      *reinterpret_cast<uint2*>((char*)pl + pa[t]) = make_uint2(u01, u23);
    }

    // ---- O += P'.V ; denom += P'.ones (exact row-sums via MFMA) ----
    __builtin_amdgcn_s_setprio(1);
    #pragma unroll
    for (int kc = 0; kc < 2; ++kc){
      f16x8 af = *reinterpret_cast<const f16x8*>((const char*)pl + SWZ(lc, lg*16 + kc*64));
      accd = __builtin_amdgcn_mfma_f32_16x16x32_f16(af, onesf, accd, 0, 0, 0);
      #pragma unroll
      for (int t2 = 0; t2 < 4; ++t2){
        f16x8 vf = *reinterpret_cast<const f16x8*>((const char*)Vt[cur] + SWZ(t2*16 + lc, lg*16 + kc*64));
        acc[t2] = __builtin_amdgcn_mfma_f32_16x16x32_f16(af, vf, acc[t2], 0, 0, 0);
      }
    }
    __builtin_amdgcn_s_setprio(0);
    cur ^= 1;
  }
#undef STAGE

  // ---- normalize + store (n,q,h,d); accd[r] = Σ_k P'[q=lg*4+r] (complete, no shuffles) ----
  #pragma unroll
  for (int r = 0; r < 4; ++r){
    float inv = 1.0f / (1024.0f + accd[r]);
    size_t qg = (size_t)(n*1024 + qbase + lg*4 + r);
    unsigned short* op = Obf + (qg * 16 + h) * 64;
    unsigned w01 = pk2(acc[0][r]*inv, acc[1][r]*inv);
    unsigned w23 = pk2(acc[2][r]*inv, acc[3][r]*inv);
    op[0*16 + lc] = (unsigned short)w01;
    op[1*16 + lc] = (unsigned short)(w01 >> 16);
    op[2*16 + lc] = (unsigned short)w23;
    op[3*16 + lc] = (unsigned short)(w23 >> 16);
  }
}

// ---------------- out = O @ W^T + b  (8192x1024x1024 bf16 GEMM, DMA-staged, dbuf) ----------------
__global__ __launch_bounds__(256) void out_gemm_kernel(
    const unsigned short* __restrict__ A, const unsigned short* __restrict__ B,
    const float* __restrict__ bias, float* __restrict__ out)
{
  __shared__ __attribute__((aligned(16))) unsigned short As[2][128*64];
  __shared__ __attribute__((aligned(16))) unsigned short Bs[2][128*64];

  int mb = blockIdx.x;     // 64
  int nb = blockIdx.y;     // 8
  int tid = threadIdx.x, wid = tid >> 6, lane = tid & 63, lg = lane >> 4, lc = lane & 15;
  int wr = wid >> 1, wc = wid & 1;

  int rr[4], cc[4];
  #pragma unroll
  for (int i = 0; i < 4; ++i){
    int s = tid + 256*i;
    rr[i] = s >> 3;
    cc[i] = ((s & 7) * 16) ^ ((rr[i] & 7) << 4);
  }

#define GSTAGE(KB, BUF) do { \
    _Pragma("unroll") \
    for (int i = 0; i < 4; ++i){ \
      int s = tid + 256*i; \
      gld16((const char*)A + ((size_t)(mb*128 + rr[i]) * 1024 + (KB)*64) * 2 + cc[i], (char*)As[BUF] + s*16); \
      gld16((const char*)B + ((size_t)(nb*128 + rr[i]) * 1024 + (KB)*64) * 2 + cc[i], (char*)Bs[BUF] + s*16); \
    } \
  } while(0)

  f32x4 acc[4][4];
  for (int m = 0; m < 4; ++m)
    for (int nn2 = 0; nn2 < 4; ++nn2) acc[m][nn2] = (f32x4){0.f,0.f,0.f,0.f};

  GSTAGE(0, 0);
  int cur = 0;

  for (int kb = 0; kb < 16; ++kb){
    __syncthreads();
    if (kb < 15) GSTAGE(kb + 1, cur ^ 1);
    #pragma unroll
    for (int kc = 0; kc < 2; ++kc){
      bf16x8 af[4], bfr[4];
      #pragma unroll
      for (int m = 0; m < 4; ++m)
        af[m] = *reinterpret_cast<const bf16x8*>((const char*)As[cur] + SWZ(wr*64 + m*16 + lc, kc*64 + lg*16));
      #pragma unroll
      for (int nn2 = 0; nn2 < 4; ++nn2)
        bfr[nn2] = *reinterpret_cast<const bf16x8*>((const char*)Bs[cur] + SWZ(wc*64 + nn2*16 + lc, kc*64 + lg*16));
      __builtin_amdgcn_s_setprio(1);
      #pragma unroll
      for (int m = 0; m < 4; ++m)
        #pragma unroll
        for (int nn2 = 0; nn2 < 4; ++nn2)
          acc[m][nn2] = __builtin_amdgcn_mfma_f32_16x16x32_bf16(af[m], bfr[nn2], acc[m][nn2], 0, 0, 0);
      __builtin_amdgcn_s_setprio(0);
    }
    cur ^= 1;
  }
#undef GSTAGE

  for (int nn2 = 0; nn2 < 4; ++nn2){
    int col = nb*128 + wc*64 + nn2*16 + lc;
    float bv = bias[col];
    for (int m = 0; m < 4; ++m){
      int rowb = mb*128 + wr*64 + m*16 + lg*4;
      for (int r = 0; r < 4; ++r)
        out[(size_t)(rowb + r) * 1024 + col] = acc[m][nn2][r] + bv;
    }
  }
}

extern "C" void kernel_launch(void* const* d_in, const int* in_sizes, int n_in,
                              void* d_out, int out_size, void* d_ws, size_t ws_size,
                              hipStream_t stream) {
  const float* V  = (const float*)d_in[0];
  const float* K  = (const float*)d_in[1];
  const float* Q  = (const float*)d_in[2];
  const int* mask = (const int*)d_in[3];
  const float* W  = (const float*)d_in[4];
  const float* b  = (const float*)d_in[5];
  float* out = (float*)d_out;

  char* ws = (char*)d_ws;
  unsigned short* Wb    = (unsigned short*)ws;               // 2 MB
  unsigned short* Obf   = (unsigned short*)(ws + (2u<<20));  // 16.78 MB
  unsigned char*  Mex8  = (unsigned char*)(ws + (19u<<20));  // 8.39 MB
  float*          Vpart = (float*)(ws + (28u<<20));          // 0.5 MB
  // Kb + Vtg live in d_out (33.55 MB, fully overwritten by the final GEMM afterwards)
  unsigned short* Kb  = (unsigned short*)d_out;              // 16.78 MB
  unsigned short* Vtg = Kb + (size_t)8*1024*1024;            // 16.78 MB

  maskex_kernel<<<2048, 256, 0, stream>>>(mask, (unsigned*)Mex8);
  wconv_kernel<<<1024, 256, 0, stream>>>(W, Wb);
  permqk_kernel<<<4096, 256, 0, stream>>>(K, Kb);
  permv_kernel<<<2048, 256, 0, stream>>>(V, Vtg, Vpart);
  attn_kernel<<<2048, 256, 0, stream>>>(Q, Kb, Vtg, Mex8, Vpart, Obf);
  dim3 g(64, 8);
  out_gemm_kernel<<<g, 256, 0, stream>>>(Obf, Wb, b, out);
}

// Round 11
// 137.823 us; speedup vs baseline: 1.1152x; 1.1152x over previous
//
#include <hip/hip_runtime.h>
#include <hip/hip_bf16.h>

typedef __attribute__((ext_vector_type(8))) short bf16x8;
typedef __attribute__((ext_vector_type(4))) float f32x4;

// Swizzled byte address for 128-byte rows: XOR row bits into the 16B-slot index.
#define SWZ(row, byteofs) (((row)*128) + ((byteofs) ^ (((row)&7)<<4)))

__device__ __forceinline__ unsigned pk2(float a, float b){
  __hip_bfloat162 h = __float22bfloat162_rn(make_float2(a, b));   // v_cvt_pk_bf16_f32
  unsigned u; __builtin_memcpy(&u, &h, 4);
  return u;
}

__device__ __forceinline__ void gld16(const void* g, void* l){
  __builtin_amdgcn_global_load_lds((const __attribute__((address_space(1))) void*)g,
                                   (__attribute__((address_space(3))) void*)l, 16, 0, 0);
}

union bfpack { bf16x8 v; unsigned u[4]; uint4 q; };

// ---------------- mask -> bitmask (1 bit per (q,k)) ----------------
__global__ __launch_bounds__(256) void mask_bits_kernel(const int* __restrict__ mask,
                                                        unsigned* __restrict__ bits){
  int t = blockIdx.x * 256 + threadIdx.x;
  int u = t >> 6;
  int lane = t & 63;
  int row = u >> 4;        // n*1024 + q
  int chunk = u & 15;
  int m = mask[(size_t)row * 1024 + chunk * 64 + lane];
  unsigned long long b = __ballot(m != 0);
  if (lane == 0){
    unsigned* p = bits + row * 32 + chunk * 2;
    p[0] = (unsigned)(b & 0xffffffffull);
    p[1] = (unsigned)(b >> 32);
  }
}

// ---------------- W fp32 -> bf16 ----------------
__global__ __launch_bounds__(256) void wconv_kernel(const float* __restrict__ W,
                                                    unsigned short* __restrict__ Wb){
  int i = blockIdx.x * 256 + threadIdx.x;
  float4 f = reinterpret_cast<const float4*>(W)[i];
  uint2 o = make_uint2(pk2(f.x, f.y), pk2(f.z, f.w));
  reinterpret_cast<uint2*>(Wb)[i] = o;
}

// ---------------- K permute: (n, L, h*64) f32 -> (n, h, L, 64) bf16 ----------------
__global__ __launch_bounds__(256) void permqk_kernel(const float* __restrict__ src,
                                                     unsigned short* __restrict__ dst){
  int w = blockIdx.x * 4 + (threadIdx.x >> 6);   // 16384 waves: n(8) x h(16) x l8(128)
  int lane = threadIdx.x & 63;
  int n = w >> 11, h = (w >> 7) & 15, l8 = w & 127;
  int l = l8 * 8 + (lane >> 3);
  int dch = (lane & 7) * 8;
  const float* sp = src + ((size_t)n * 1024 + l) * 1024 + h * 64 + dch;
  float4 a = *reinterpret_cast<const float4*>(sp);
  float4 b = *reinterpret_cast<const float4*>(sp + 4);
  uint4 o = make_uint4(pk2(a.x,a.y), pk2(a.z,a.w), pk2(b.x,b.y), pk2(b.z,b.w));
  *reinterpret_cast<uint4*>(dst + (((size_t)n * 16 + h) * 1024 + l) * 64 + dch) = o;
}

// ---------------- V permute+transpose: (n, L, h*64) f32 -> (n, h, 64, L) bf16 ----------------
__global__ __launch_bounds__(256) void permv_kernel(const float* __restrict__ src,
                                                    unsigned short* __restrict__ dst){
  __shared__ __attribute__((aligned(16))) unsigned short T[64*64];  // [l][d], swizzled rows
  int bid = blockIdx.x;                   // 2048 = n(8) x h(16) x ltile(16)
  int n = bid >> 8, h = (bid >> 4) & 15, l0 = (bid & 15) * 64;
  int t = threadIdx.x;
  {
    int l = t >> 2, dseg = t & 3;
    const float* sp = src + ((size_t)n * 1024 + l0 + l) * 1024 + h * 64 + dseg * 16;
    float4 f0 = *reinterpret_cast<const float4*>(sp + 0);
    float4 f1 = *reinterpret_cast<const float4*>(sp + 4);
    float4 f2 = *reinterpret_cast<const float4*>(sp + 8);
    float4 f3 = *reinterpret_cast<const float4*>(sp + 12);
    uint4 lo = make_uint4(pk2(f0.x,f0.y), pk2(f0.z,f0.w), pk2(f1.x,f1.y), pk2(f1.z,f1.w));
    uint4 hi = make_uint4(pk2(f2.x,f2.y), pk2(f2.z,f2.w), pk2(f3.x,f3.y), pk2(f3.z,f3.w));
    *reinterpret_cast<uint4*>((char*)T + SWZ(l, dseg*32))      = lo;
    *reinterpret_cast<uint4*>((char*)T + SWZ(l, dseg*32 + 16)) = hi;
  }
  __syncthreads();
  {
    int d = t >> 2, lseg = t & 3;
    for (int j = 0; j < 2; ++j){
      bf16x8 wv;
      #pragma unroll
      for (int i = 0; i < 8; ++i){
        int l = lseg*16 + j*8 + i;        // l&7 == i (static per unrolled i)
        wv[i] = *(const short*)((const char*)T + (size_t)l*128 + ((d*2) ^ (i<<4)));
      }
      *reinterpret_cast<bf16x8*>(dst + (((size_t)n * 16 + h) * 64 + d) * 1024 + l0 + lseg*16 + j*8) = wv;
    }
  }
}

// -------- flash attention (single-buffered K/V, split-phase 2-barrier schedule) --------
// grid: 2048 blocks = (n:8) x (h:16) x (qb:16), 256 threads (4 waves x 16 q-rows)
// LDS = 8K(Kt) + 8K(Vt) + 8K(Pl) = 24 KB -> 6 blocks/CU (was 40 KB -> 4)
__global__ __launch_bounds__(256) void attn_kernel(
    const float* __restrict__ Q, const unsigned short* __restrict__ Kb,
    const unsigned short* __restrict__ Vtg, const unsigned* __restrict__ bits,
    unsigned short* __restrict__ Obf)
{
  __shared__ __attribute__((aligned(16))) unsigned short Kt[64*64];   // [key][d], swizzled
  __shared__ __attribute__((aligned(16))) unsigned short Vt[64*64];   // [d][key], swizzled
  __shared__ __attribute__((aligned(16))) unsigned short Pl[4][16*64];// per-wave P, swizzled

  int bid = blockIdx.x;
  int wg = ((bid & 7) << 8) | (bid >> 3);   // XCD-contiguous chunks of 256
  int qb = wg & 15, h = (wg >> 4) & 15, n = wg >> 8;

  int tid = threadIdx.x, wid = tid >> 6, lane = tid & 63, lg = lane >> 4, lc = lane & 15;
  int qbase = qb * 64 + wid * 16;

  const unsigned short* Kh = Kb  + ((size_t)(n*16 + h)) * 1024 * 64;
  const unsigned short* Vh = Vtg + ((size_t)(n*16 + h)) * 64 * 1024;

  // Q fragment from original fp32 layout (one-time)
  bf16x8 qf[2];
  {
    const float* qp = Q + (size_t)(n*1024 + qbase + lc) * 1024 + h*64;
    #pragma unroll
    for (int c = 0; c < 2; ++c){
      float4 a0 = *reinterpret_cast<const float4*>(qp + c*32 + lg*8);
      float4 a1 = *reinterpret_cast<const float4*>(qp + c*32 + lg*8 + 4);
      bfpack pk;
      pk.u[0] = pk2(a0.x,a0.y); pk.u[1] = pk2(a0.z,a0.w);
      pk.u[2] = pk2(a1.x,a1.y); pk.u[3] = pk2(a1.z,a1.w);
      qf[c] = pk.v;
    }
  }

  // staging slots: slot s -> LDS byte 16s == SWZ(row=s>>3, col=(s&7)*16 ^ ((row&7)<<4))
  const int s0 = tid, s1 = tid + 256;
  const int r0 = s0 >> 3, c0 = ((s0 & 7) * 16) ^ ((r0 & 7) << 4);
  const int r1 = s1 >> 3, c1 = ((s1 & 7) * 16) ^ ((r1 & 7) << 4);

#define STAGE_K(KB) do { \
    gld16((const char*)Kh + ((size_t)((KB)*64 + r0) * 128 + c0), (char*)Kt + s0*16); \
    gld16((const char*)Kh + ((size_t)((KB)*64 + r1) * 128 + c1), (char*)Kt + s1*16); \
  } while(0)
#define STAGE_V(KB) do { \
    gld16((const char*)Vh + ((size_t)r0 * 2048 + (KB)*128 + c0), (char*)Vt + s0*16); \
    gld16((const char*)Vh + ((size_t)r1 * 2048 + (KB)*128 + c1), (char*)Vt + s1*16); \
  } while(0)

  f32x4 acc[4];
  for (int i = 0; i < 4; ++i) acc[i] = (f32x4){0.f,0.f,0.f,0.f};
  float lsum[4] = {0.f,0.f,0.f,0.f};
  const float scale = 0.03125f;   // 1/sqrt(1024)

  STAGE_K(0);     // drained at first syncA

  for (int kb = 0; kb < 16; ++kb){
    __syncthreads();            // syncA: K_kb staged (all waves); PV readers of V_{kb-1} done
    STAGE_V(kb);                // V_kb in flight under QK^T + softmax

    // mask words
    unsigned words[4][2];
    {
      const unsigned* bp = bits + (size_t)(n*1024 + qbase + lg*4) * 32 + kb*2;
      #pragma unroll
      for (int r = 0; r < 4; ++r){ words[r][0] = bp[r*32]; words[r][1] = bp[r*32 + 1]; }
    }

    // ---- S = Q . K^T ----
    f32x4 S[4];
    #pragma unroll
    for (int t = 0; t < 4; ++t) S[t] = (f32x4){0.f,0.f,0.f,0.f};
    __builtin_amdgcn_s_setprio(1);
    #pragma unroll
    for (int t = 0; t < 4; ++t)
      #pragma unroll
      for (int c = 0; c < 2; ++c){
        bf16x8 kf = *reinterpret_cast<const bf16x8*>((const char*)Kt + SWZ(t*16 + lc, lg*16 + c*64));
        S[t] = __builtin_amdgcn_mfma_f32_16x16x32_bf16(qf[c], kf, S[t], 0, 0, 0);
      }
    __builtin_amdgcn_s_setprio(0);

    // ---- static softmax: p = masked ? 1.0 : exp(S/32) ----
    float p[4][4];
    #pragma unroll
    for (int t = 0; t < 4; ++t){
      int bitidx = ((t & 1) << 4) + lc;
      #pragma unroll
      for (int r = 0; r < 4; ++r){
        bool mk = (words[r][t>>1] >> bitidx) & 1u;
        p[t][r] = mk ? __expf(S[t][r] * scale) : 1.0f;
      }
    }
    #pragma unroll
    for (int r = 0; r < 4; ++r)
      lsum[r] += (p[0][r] + p[1][r]) + (p[2][r] + p[3][r]);

    // ---- P -> bf16 (cvt_pk) -> per-wave LDS (A-fragment relayout) ----
    unsigned short* pl = &Pl[wid][0];
    #pragma unroll
    for (int t = 0; t < 4; ++t){
      unsigned w01 = pk2(p[t][0], p[t][1]);
      unsigned w23 = pk2(p[t][2], p[t][3]);
      int colb = (t*16 + lc)*2;
      *(unsigned short*)((char*)pl + SWZ(lg*4 + 0, colb)) = (unsigned short)w01;
      *(unsigned short*)((char*)pl + SWZ(lg*4 + 1, colb)) = (unsigned short)(w01 >> 16);
      *(unsigned short*)((char*)pl + SWZ(lg*4 + 2, colb)) = (unsigned short)w23;
      *(unsigned short*)((char*)pl + SWZ(lg*4 + 3, colb)) = (unsigned short)(w23 >> 16);
    }

    __syncthreads();            // syncB: V_kb staged; all waves' QK^T reads of Kt done
    if (kb < 15) STAGE_K(kb+1); // K_{kb+1} in flight under PV (+ next syncA)

    // ---- O += P . V ----
    __builtin_amdgcn_s_setprio(1);
    #pragma unroll
    for (int kc = 0; kc < 2; ++kc){
      bf16x8 af = *reinterpret_cast<const bf16x8*>((const char*)pl + SWZ(lc, lg*16 + kc*64));
      #pragma unroll
      for (int t2 = 0; t2 < 4; ++t2){
        bf16x8 vf = *reinterpret_cast<const bf16x8*>((const char*)Vt + SWZ(t2*16 + lc, lg*16 + kc*64));
        acc[t2] = __builtin_amdgcn_mfma_f32_16x16x32_bf16(af, vf, acc[t2], 0, 0, 0);
      }
    }
    __builtin_amdgcn_s_setprio(0);
  }
#undef STAGE_K
#undef STAGE_V

  // ---- final sum-reduce across the 16-lane group, normalize, store (n,q,h,d) ----
  #pragma unroll
  for (int r = 0; r < 4; ++r){
    float s = lsum[r];
    for (int d = 1; d < 16; d <<= 1) s += __shfl_xor(s, d, 64);
    float inv = 1.0f / s;
    size_t qg = (size_t)(n*1024 + qbase + lg*4 + r);
    unsigned short* op = Obf + (qg * 16 + h) * 64;
    unsigned w01 = pk2(acc[0][r]*inv, acc[1][r]*inv);
    unsigned w23 = pk2(acc[2][r]*inv, acc[3][r]*inv);
    op[0*16 + lc] = (unsigned short)w01;
    op[1*16 + lc] = (unsigned short)(w01 >> 16);
    op[2*16 + lc] = (unsigned short)w23;
    op[3*16 + lc] = (unsigned short)(w23 >> 16);
  }
}

// ---------------- out = O @ W^T + b  (8192x1024x1024 bf16 GEMM, DMA-staged, dbuf) ----------------
__global__ __launch_bounds__(256) void out_gemm_kernel(
    const unsigned short* __restrict__ A, const unsigned short* __restrict__ B,
    const float* __restrict__ bias, float* __restrict__ out)
{
  __shared__ __attribute__((aligned(16))) unsigned short As[2][128*64];
  __shared__ __attribute__((aligned(16))) unsigned short Bs[2][128*64];

  int mb = blockIdx.x;     // 64
  int nb = blockIdx.y;     // 8
  int tid = threadIdx.x, wid = tid >> 6, lane = tid & 63, lg = lane >> 4, lc = lane & 15;
  int wr = wid >> 1, wc = wid & 1;

  int rr[4], cc[4];
  #pragma unroll
  for (int i = 0; i < 4; ++i){
    int s = tid + 256*i;
    rr[i] = s >> 3;
    cc[i] = ((s & 7) * 16) ^ ((rr[i] & 7) << 4);
  }

#define GSTAGE(KB, BUF) do { \
    _Pragma("unroll") \
    for (int i = 0; i < 4; ++i){ \
      int s = tid + 256*i; \
      gld16((const char*)A + ((size_t)(mb*128 + rr[i]) * 1024 + (KB)*64) * 2 + cc[i], (char*)As[BUF] + s*16); \
      gld16((const char*)B + ((size_t)(nb*128 + rr[i]) * 1024 + (KB)*64) * 2 + cc[i], (char*)Bs[BUF] + s*16); \
    } \
  } while(0)

  f32x4 acc[4][4];
  for (int m = 0; m < 4; ++m)
    for (int nn2 = 0; nn2 < 4; ++nn2) acc[m][nn2] = (f32x4){0.f,0.f,0.f,0.f};

  GSTAGE(0, 0);
  int cur = 0;

  for (int kb = 0; kb < 16; ++kb){
    __syncthreads();
    if (kb < 15) GSTAGE(kb + 1, cur ^ 1);
    #pragma unroll
    for (int kc = 0; kc < 2; ++kc){
      bf16x8 af[4], bfr[4];
      #pragma unroll
      for (int m = 0; m < 4; ++m)
        af[m] = *reinterpret_cast<const bf16x8*>((const char*)As[cur] + SWZ(wr*64 + m*16 + lc, kc*64 + lg*16));
      #pragma unroll
      for (int nn2 = 0; nn2 < 4; ++nn2)
        bfr[nn2] = *reinterpret_cast<const bf16x8*>((const char*)Bs[cur] + SWZ(wc*64 + nn2*16 + lc, kc*64 + lg*16));
      __builtin_amdgcn_s_setprio(1);
      #pragma unroll
      for (int m = 0; m < 4; ++m)
        #pragma unroll
        for (int nn2 = 0; nn2 < 4; ++nn2)
          acc[m][nn2] = __builtin_amdgcn_mfma_f32_16x16x32_bf16(af[m], bfr[nn2], acc[m][nn2], 0, 0, 0);
      __builtin_amdgcn_s_setprio(0);
    }
    cur ^= 1;
  }
#undef GSTAGE

  for (int nn2 = 0; nn2 < 4; ++nn2){
    int col = nb*128 + wc*64 + nn2*16 + lc;
    float bv = bias[col];
    for (int m = 0; m < 4; ++m){
      int rowb = mb*128 + wr*64 + m*16 + lg*4;
      for (int r = 0; r < 4; ++r)
        out[(size_t)(rowb + r) * 1024 + col] = acc[m][nn2][r] + bv;
    }
  }
}

extern "C" void kernel_launch(void* const* d_in, const int* in_sizes, int n_in,
                              void* d_out, int out_size, void* d_ws, size_t ws_size,
                              hipStream_t stream) {
  const float* V  = (const float*)d_in[0];
  const float* K  = (const float*)d_in[1];
  const float* Q  = (const float*)d_in[2];
  const int* mask = (const int*)d_in[3];
  const float* W  = (const float*)d_in[4];
  const float* b  = (const float*)d_in[5];
  float* out = (float*)d_out;

  char* ws = (char*)d_ws;
  unsigned* bits       = (unsigned*)ws;                      // 1 MB
  unsigned short* Wb   = (unsigned short*)(ws + (1u<<20));   // 2 MB
  unsigned short* Obf  = (unsigned short*)(ws + (3u<<20));   // 16 MB
  unsigned short* Vtg  = (unsigned short*)(ws + (19u<<20));  // 16 MB
  // Kb lives in d_out (32 MB, fully overwritten by the final GEMM afterwards)
  unsigned short* Kb   = (unsigned short*)d_out;             // 16 MB

  mask_bits_kernel<<<32768, 256, 0, stream>>>(mask, bits);
  wconv_kernel<<<1024, 256, 0, stream>>>(W, Wb);
  permqk_kernel<<<4096, 256, 0, stream>>>(K, Kb);
  permv_kernel<<<2048, 256, 0, stream>>>(V, Vtg);
  attn_kernel<<<2048, 256, 0, stream>>>(Q, Kb, Vtg, bits, Obf);
  dim3 g(64, 8);
  out_gemm_kernel<<<g, 256, 0, stream>>>(Obf, Wb, b, out);
}